// Round 10
// baseline (164.689 us; speedup 1.0000x reference)
//
#include <hip/hip_runtime.h>
#include <math.h>

// Problem constants (from reference)
#define GAMMA 0.98f
#define LBDA  0.93f
#define GL    (GAMMA * LBDA)   // gamma*lambda
constexpr int B  = 2048;
constexpr int T  = 1024;

// clang ext_vector types — required by __builtin_nontemporal_load
// (HIP_vector_type wrappers are rejected; these have identical layout/align)
typedef float f32x4 __attribute__((ext_vector_type(4)));
typedef float f32x2 __attribute__((ext_vector_type(2)));
typedef int   i32x2 __attribute__((ext_vector_type(2)));

// ---------------------------------------------------------------------------
// log_pi = x[a] - logsumexp(x[0..5])
// ---------------------------------------------------------------------------
__device__ __forceinline__ float logpi(float x0, float x1, float x2,
                                       float x3, float x4, float x5, int a) {
    float m = fmaxf(fmaxf(fmaxf(x0, x1), fmaxf(x2, x3)), fmaxf(x4, x5));
    float s = __expf(x0 - m) + __expf(x1 - m) + __expf(x2 - m) +
              __expf(x3 - m) + __expf(x4 - m) + __expf(x5 - m);
    float lse = m + __logf(s);
    float r = x0;
    r = (a == 1) ? x1 : r;
    r = (a == 2) ? x2 : r;
    r = (a == 3) ? x3 : r;
    r = (a == 4) ? x4 : r;
    r = (a == 5) ? x5 : r;
    return r - lse;
}

// ---------------------------------------------------------------------------
// Fused kernel: one block (512 threads = 8 waves) per batch row; thread j
// owns timesteps t = 2j, 2j+1. Round-10 = round-9 retry: NONTEMPORAL loads
// on all single-use input streams (logits, logits_old, rewards, dones,
// actions) via ext_vector_type pointers. Rounds 4-8 established the kernel
// is invariant (~46-50us, ~3.1 TB/s effective) under coalescing/LDS/barrier/
// VGPR changes; remaining suspect is cache-allocation churn against the
// harness's 268MB poison + 145MB restore writes preceding each replay.
// values is read twice (vl2 + vl1 lookahead) -> stays temporal.
// Reverse recurrences (returns Rs, GAE A) via affine-map suffix composition:
// local map -> wave suffix scan -> 8-wave LDS fixup -> replay with exact
// carry. Block partials -> private slots (no contended atomics).
// ---------------------------------------------------------------------------
__global__ __launch_bounds__(512) void k_fused(
        const float* __restrict__ rwp, const float* __restrict__ vlp,
        const int* __restrict__ dnp, const int* __restrict__ acp,
        const float* __restrict__ lgp, const float* __restrict__ lgop,
        float* __restrict__ part_e, float* __restrict__ part_v,
        float* __restrict__ part_p) {
    int j = threadIdx.x;
    int b = blockIdx.x;

    const f32x4* Lrow = (const f32x4*)lgp  + (size_t)b * 1536;  // 1536 f32x4/row
    const f32x4* Orow = (const f32x4*)lgop + (size_t)b * 1536;
    const f32x2* rw2  = (const f32x2*)rwp;
    const f32x2* vl2  = (const f32x2*)vlp;
    const i32x2* dn2  = (const i32x2*)dnp;
    const i32x2* ac2  = (const i32x2*)acp;
    int rbase = b * 512 + j;                        // f32x2/i32x2 row index

    // all global loads issued up front; single-use streams marked nontemporal
    f32x4 A0 = __builtin_nontemporal_load(&Lrow[3 * j]);
    f32x4 A1 = __builtin_nontemporal_load(&Lrow[3 * j + 1]);
    f32x4 A2 = __builtin_nontemporal_load(&Lrow[3 * j + 2]);
    f32x4 B0 = __builtin_nontemporal_load(&Orow[3 * j]);
    f32x4 B1 = __builtin_nontemporal_load(&Orow[3 * j + 1]);
    f32x4 B2 = __builtin_nontemporal_load(&Orow[3 * j + 2]);
    f32x2 rw = __builtin_nontemporal_load(&rw2[rbase]);
    f32x2 vlv = vl2[rbase];                         // values: read twice, cached
    i32x2 dn = __builtin_nontemporal_load(&dn2[rbase]);
    i32x2 aa = __builtin_nontemporal_load(&ac2[rbase]);
    int vidx = 2 * j + 2;                           // values[t+2]
    vidx = (vidx > 1022) ? 1022 : vidx;             // j=511: loaded but unused
    float vnext = vlp[(size_t)b * T + vidx];

    float lp0  = logpi(A0.x, A0.y, A0.z, A0.w, A1.x, A1.y, aa.x);
    float lp1  = logpi(A1.z, A1.w, A2.x, A2.y, A2.z, A2.w, aa.y);
    float lpo0 = logpi(B0.x, B0.y, B0.z, B0.w, B1.x, B1.y, aa.x);
    float lpo1 = logpi(B1.z, B1.w, B2.x, B2.y, B2.z, B2.w, aa.y);
    float rr0 = __expf(lp0 - lpo0), rr1 = __expf(lp1 - lpo1);

    __shared__ float wa1[8], wb1[8], wa2[8], wb2[8];
    __shared__ float red[24];

    // ---- per-thread affine maps for the two recurrences -------------------
    float rwk[2] = {rw.x, rw.y};
    float vk[3]  = {vlv.x, vlv.y, vnext};
    int   dk[2]  = {dn.x, dn.y};

    float b1[2], c1[2], b2[2], c2[2];
    #pragma unroll
    for (int k = 0; k < 2; ++k) {
        bool d = dk[k] != 0;
        c1[k] = d ? 0.0f : GAMMA;
        b1[k] = rwk[k];
        c2[k] = d ? 0.0f : GL;
        b2[k] = rwk[k] + (d ? 0.0f : GAMMA * vk[k + 1]) - vk[k];  // td error
    }
    if (j == 511) {  // t = T-1: Rs[T-1] = d ? r : v ; A[T-1] = 0
        b1[1] = dk[1] ? rwk[1] : vk[1];
        c1[1] = 0.0f;
        b2[1] = 0.0f;
        c2[1] = 0.0f;
    }

    // local suffix composition over k = 1..0
    float a1 = 1.0f, bb1 = 0.0f, a2 = 1.0f, bb2 = 0.0f;
    #pragma unroll
    for (int k = 1; k >= 0; --k) {
        bb1 = b1[k] + c1[k] * bb1;  a1 = c1[k] * a1;
        bb2 = b2[k] + c2[k] * bb2;  a2 = c2[k] * a2;
    }

    // wave-level inclusive SUFFIX scan of affine maps
    int lane = j & 63, wv = j >> 6;
    #pragma unroll
    for (int d = 1; d < 64; d <<= 1) {
        float an1 = __shfl_down(a1, d), bn1 = __shfl_down(bb1, d);
        float an2 = __shfl_down(a2, d), bn2 = __shfl_down(bb2, d);
        if (lane + d < 64) {
            bb1 = a1 * bn1 + bb1;  a1 = a1 * an1;
            bb2 = a2 * bn2 + bb2;  a2 = a2 * an2;
        }
    }
    if (lane == 0) { wa1[wv] = a1; wb1[wv] = bb1; wa2[wv] = a2; wb2[wv] = bb2; }
    float a1s = __shfl_down(a1, 1), b1s = __shfl_down(bb1, 1);
    float a2s = __shfl_down(a2, 1), b2s = __shfl_down(bb2, 1);
    __syncthreads();

    // carry entering this wave's high end (apply later waves' maps to 0)
    float x1 = 0.0f, x2 = 0.0f;
    for (int w2 = 7; w2 > wv; --w2) {
        x1 = wa1[w2] * x1 + wb1[w2];
        x2 = wa2[w2] * x2 + wb2[w2];
    }
    float cin1 = (lane == 63) ? x1 : (a1s * x1 + b1s);
    float cin2 = (lane == 63) ? x2 : (a2s * x2 + b2s);

    // replay with exact carries, accumulate losses
    float rrk[2] = {rr0, rr1};
    float vsum = 0.0f, psum = 0.0f;
    float R = cin1, A = cin2;
    #pragma unroll
    for (int k = 1; k >= 0; --k) {
        R = b1[k] + c1[k] * R;
        float dv = R - vk[k];
        vsum += dv * dv;
        A = b2[k] + c2[k] * A;
        if (2 * j + k < T - 1) {
            // faithful torch clip(min=0.8,max=0.2) -> r_clipped == 0.2
            psum += fminf(rrk[k] * A, 0.2f * A);
        }
    }
    float es = lp0 + lp1;

    #pragma unroll
    for (int d = 32; d; d >>= 1) {
        es   += __shfl_xor(es, d);
        vsum += __shfl_xor(vsum, d);
        psum += __shfl_xor(psum, d);
    }
    if (lane == 0) { red[wv] = es; red[8 + wv] = vsum; red[16 + wv] = psum; }
    __syncthreads();
    if (j == 0) {
        float te = 0.0f, tv = 0.0f, tp = 0.0f;
        #pragma unroll
        for (int w2 = 0; w2 < 8; ++w2) {
            te += red[w2]; tv += red[8 + w2]; tp += red[16 + w2];
        }
        part_e[b] = te;
        part_v[b] = tv;
        part_p[b] = tp;
    }
}

// ---------------------------------------------------------------------------
// Finalize: single-block reduction of 3 x B partials -> 3 outputs.
// ---------------------------------------------------------------------------
__global__ __launch_bounds__(256) void k_fin(
        const float* __restrict__ part_e, const float* __restrict__ part_v,
        const float* __restrict__ part_p, float* __restrict__ out) {
    int tid = threadIdx.x;
    float e = 0.0f, v = 0.0f, p = 0.0f;
    for (int i = tid; i < B; i += 256) {
        e += part_e[i];
        v += part_v[i];
        p += part_p[i];
    }
    #pragma unroll
    for (int d = 32; d; d >>= 1) {
        e += __shfl_xor(e, d);
        v += __shfl_xor(v, d);
        p += __shfl_xor(p, d);
    }
    __shared__ float sm[12];
    int lane = tid & 63, wv = tid >> 6;
    if (lane == 0) { sm[wv] = e; sm[4 + wv] = v; sm[8 + wv] = p; }
    __syncthreads();
    if (tid == 0) {
        float te = sm[0] + sm[1] + sm[2] + sm[3];
        float tv = sm[4] + sm[5] + sm[6] + sm[7];
        float tp = sm[8] + sm[9] + sm[10] + sm[11];
        out[0] = -tp / (float)(B * (T - 1));   // ppo_loss
        out[1] =  tv / (float)(B * T);         // value_loss
        out[2] = -te / (float)(B * T);         // entropy_loss
    }
}

// ---------------------------------------------------------------------------
extern "C" void kernel_launch(void* const* d_in, const int* in_sizes, int n_in,
                              void* d_out, int out_size, void* d_ws, size_t ws_size,
                              hipStream_t stream) {
    const float* rewards    = (const float*)d_in[0];
    const float* values     = (const float*)d_in[1];
    const float* logits     = (const float*)d_in[2];
    const float* logits_old = (const float*)d_in[3];
    const int*   dones      = (const int*)d_in[4];
    const int*   actions    = (const int*)d_in[5];

    float* part_e = (float*)d_ws;       // B floats
    float* part_v = part_e + B;         // B floats
    float* part_p = part_v + B;         // B floats

    k_fused<<<B, 512, 0, stream>>>(
        rewards, values, dones, actions, logits, logits_old,
        part_e, part_v, part_p);

    k_fin<<<1, 256, 0, stream>>>(part_e, part_v, part_p, (float*)d_out);
}

// Round 11
// 154.811 us; speedup vs baseline: 1.0638x; 1.0638x over previous
//
#include <hip/hip_runtime.h>
#include <math.h>

// Problem constants (from reference)
#define GAMMA 0.98f
#define LBDA  0.93f
#define GL    (GAMMA * LBDA)   // gamma*lambda
constexpr int B  = 2048;
constexpr int T  = 1024;

// clang ext_vector types — required by __builtin_nontemporal_load
typedef float f32x4 __attribute__((ext_vector_type(4)));
typedef float f32x2 __attribute__((ext_vector_type(2)));
typedef int   i32x2 __attribute__((ext_vector_type(2)));

// ---------------------------------------------------------------------------
// log_pi = x[a] - logsumexp(x[0..5])
// ---------------------------------------------------------------------------
__device__ __forceinline__ float logpi(float x0, float x1, float x2,
                                       float x3, float x4, float x5, int a) {
    float m = fmaxf(fmaxf(fmaxf(x0, x1), fmaxf(x2, x3)), fmaxf(x4, x5));
    float s = __expf(x0 - m) + __expf(x1 - m) + __expf(x2 - m) +
              __expf(x3 - m) + __expf(x4 - m) + __expf(x5 - m);
    float lse = m + __logf(s);
    float r = x0;
    r = (a == 1) ? x1 : r;
    r = (a == 2) ? x2 : r;
    r = (a == 3) ? x3 : r;
    r = (a == 4) ? x4 : r;
    r = (a == 5) ? x5 : r;
    return r - lse;
}

// LDS float4-index swizzle: permutes within aligned groups of 8 so stride-1
// writes stay conflict-free and stride-3 reads spread across bank groups
// (residual ~5% conflicts measured in R4/R8 — benign).
__device__ __forceinline__ int sw(int m) { return m ^ ((m >> 3) & 7); }

// ---------------------------------------------------------------------------
// Fused kernel: one block (512 threads = 8 waves) per batch row; thread j
// owns timesteps t = 2j, 2j+1. Round-11 = the two individually-tested
// mechanisms COMBINED:
//   * NONTEMPORAL loads on all single-use streams (R10: kernel 47->~<40us —
//     bypasses cache-allocation churn against the harness's 268MB poison +
//     145MB restore writes preceding each replay);
//   * wave-private LDS staging for the logits (R8 structure): stride-1
//     16B-lane coalesced global loads, readback at stride 3 (swizzled),
//     same-wave ds ordering via lgkmcnt only — zero staging barriers.
// values stays temporal (read twice: vl2 + vl1 lookahead).
// Reverse recurrences (returns Rs, GAE A) via affine-map suffix composition:
// local map -> wave suffix scan -> 8-wave LDS fixup (single barrier) ->
// replay with exact carry. Block partials -> private slots (no atomics).
// ---------------------------------------------------------------------------
__global__ __launch_bounds__(512) void k_fused(
        const float* __restrict__ rwp, const float* __restrict__ vlp,
        const int* __restrict__ dnp, const int* __restrict__ acp,
        const float* __restrict__ lgp, const float* __restrict__ lgop,
        float* __restrict__ part_e, float* __restrict__ part_v,
        float* __restrict__ part_p) {
    int j = threadIdx.x;
    int b = blockIdx.x;
    int L = j & 63, w = j >> 6;          // lane, wave

    const f32x4* Lrow = (const f32x4*)lgp  + (size_t)b * 1536;  // 1536 f32x4/row
    const f32x4* Orow = (const f32x4*)lgop + (size_t)b * 1536;
    const f32x2* rw2  = (const f32x2*)rwp;
    const f32x2* vl2  = (const f32x2*)vlp;
    const i32x2* dn2  = (const i32x2*)dnp;
    const i32x2* ac2  = (const i32x2*)acp;
    int rbase = b * 512 + j;                        // f32x2/i32x2 row index
    int wbase = w * 192;                            // wave's f32x4 offset

    // coalesced (16B lane stride) nontemporal global loads, issued up front
    f32x4 g0 = __builtin_nontemporal_load(&Lrow[wbase + L]);
    f32x4 g1 = __builtin_nontemporal_load(&Lrow[wbase + 64 + L]);
    f32x4 g2 = __builtin_nontemporal_load(&Lrow[wbase + 128 + L]);
    f32x4 h0 = __builtin_nontemporal_load(&Orow[wbase + L]);
    f32x4 h1 = __builtin_nontemporal_load(&Orow[wbase + 64 + L]);
    f32x4 h2 = __builtin_nontemporal_load(&Orow[wbase + 128 + L]);
    f32x2 rw = __builtin_nontemporal_load(&rw2[rbase]);
    f32x2 vlv = vl2[rbase];                         // values: read twice, cached
    i32x2 dn = __builtin_nontemporal_load(&dn2[rbase]);
    i32x2 aa = __builtin_nontemporal_load(&ac2[rbase]);
    int vidx = 2 * j + 2;                           // values[t+2]
    vidx = (vidx > 1022) ? 1022 : vidx;             // j=511: loaded but unused
    float vnext = vlp[(size_t)b * T + vidx];

    // wave-private staging: [w][0..192) = logits, [w][192..384) = logits_old
    __shared__ f32x4 sb[8][384];                    // 48 KB
    __shared__ float wa1[8], wb1[8], wa2[8], wb2[8];
    __shared__ float red[24];

    sb[w][sw(L)]             = g0;
    sb[w][sw(64 + L)]        = g1;
    sb[w][sw(128 + L)]       = g2;
    sb[w][192 + sw(L)]       = h0;
    sb[w][192 + sw(64 + L)]  = h1;
    sb[w][192 + sw(128 + L)] = h2;
    // same-wave ds_write -> ds_read: ordered by compiler lgkmcnt, no barrier

    int m = 3 * L;                                  // wave-local f32x4 index
    f32x4 A0 = sb[w][sw(m)], A1 = sb[w][sw(m + 1)], A2 = sb[w][sw(m + 2)];
    f32x4 B0 = sb[w][192 + sw(m)], B1 = sb[w][192 + sw(m + 1)], B2 = sb[w][192 + sw(m + 2)];

    float lp0  = logpi(A0.x, A0.y, A0.z, A0.w, A1.x, A1.y, aa.x);
    float lp1  = logpi(A1.z, A1.w, A2.x, A2.y, A2.z, A2.w, aa.y);
    float lpo0 = logpi(B0.x, B0.y, B0.z, B0.w, B1.x, B1.y, aa.x);
    float lpo1 = logpi(B1.z, B1.w, B2.x, B2.y, B2.z, B2.w, aa.y);
    float rr0 = __expf(lp0 - lpo0), rr1 = __expf(lp1 - lpo1);

    // ---- per-thread affine maps for the two recurrences -------------------
    float rwk[2] = {rw.x, rw.y};
    float vk[3]  = {vlv.x, vlv.y, vnext};
    int   dk[2]  = {dn.x, dn.y};

    float b1[2], c1[2], b2[2], c2[2];
    #pragma unroll
    for (int k = 0; k < 2; ++k) {
        bool d = dk[k] != 0;
        c1[k] = d ? 0.0f : GAMMA;
        b1[k] = rwk[k];
        c2[k] = d ? 0.0f : GL;
        b2[k] = rwk[k] + (d ? 0.0f : GAMMA * vk[k + 1]) - vk[k];  // td error
    }
    if (j == 511) {  // t = T-1: Rs[T-1] = d ? r : v ; A[T-1] = 0
        b1[1] = dk[1] ? rwk[1] : vk[1];
        c1[1] = 0.0f;
        b2[1] = 0.0f;
        c2[1] = 0.0f;
    }

    // local suffix composition over k = 1..0
    float a1 = 1.0f, bb1 = 0.0f, a2 = 1.0f, bb2 = 0.0f;
    #pragma unroll
    for (int k = 1; k >= 0; --k) {
        bb1 = b1[k] + c1[k] * bb1;  a1 = c1[k] * a1;
        bb2 = b2[k] + c2[k] * bb2;  a2 = c2[k] * a2;
    }

    // wave-level inclusive SUFFIX scan of affine maps
    #pragma unroll
    for (int d = 1; d < 64; d <<= 1) {
        float an1 = __shfl_down(a1, d), bn1 = __shfl_down(bb1, d);
        float an2 = __shfl_down(a2, d), bn2 = __shfl_down(bb2, d);
        if (L + d < 64) {
            bb1 = a1 * bn1 + bb1;  a1 = a1 * an1;
            bb2 = a2 * bn2 + bb2;  a2 = a2 * an2;
        }
    }
    if (L == 0) { wa1[w] = a1; wb1[w] = bb1; wa2[w] = a2; wb2[w] = bb2; }
    float a1s = __shfl_down(a1, 1), b1s = __shfl_down(bb1, 1);
    float a2s = __shfl_down(a2, 1), b2s = __shfl_down(bb2, 1);
    __syncthreads();                                // the one barrier

    // carry entering this wave's high end (apply later waves' maps to 0)
    float x1 = 0.0f, x2 = 0.0f;
    for (int w2 = 7; w2 > w; --w2) {
        x1 = wa1[w2] * x1 + wb1[w2];
        x2 = wa2[w2] * x2 + wb2[w2];
    }
    float cin1 = (L == 63) ? x1 : (a1s * x1 + b1s);
    float cin2 = (L == 63) ? x2 : (a2s * x2 + b2s);

    // replay with exact carries, accumulate losses
    float rrk[2] = {rr0, rr1};
    float vsum = 0.0f, psum = 0.0f;
    float R = cin1, A = cin2;
    #pragma unroll
    for (int k = 1; k >= 0; --k) {
        R = b1[k] + c1[k] * R;
        float dv = R - vk[k];
        vsum += dv * dv;
        A = b2[k] + c2[k] * A;
        if (2 * j + k < T - 1) {
            // faithful torch clip(min=0.8,max=0.2) -> r_clipped == 0.2
            psum += fminf(rrk[k] * A, 0.2f * A);
        }
    }
    float es = lp0 + lp1;

    #pragma unroll
    for (int d = 32; d; d >>= 1) {
        es   += __shfl_xor(es, d);
        vsum += __shfl_xor(vsum, d);
        psum += __shfl_xor(psum, d);
    }
    if (L == 0) { red[w] = es; red[8 + w] = vsum; red[16 + w] = psum; }
    __syncthreads();
    if (j == 0) {
        float te = 0.0f, tv = 0.0f, tp = 0.0f;
        #pragma unroll
        for (int w2 = 0; w2 < 8; ++w2) {
            te += red[w2]; tv += red[8 + w2]; tp += red[16 + w2];
        }
        part_e[b] = te;
        part_v[b] = tv;
        part_p[b] = tp;
    }
}

// ---------------------------------------------------------------------------
// Finalize: single-block reduction of 3 x B partials -> 3 outputs.
// ---------------------------------------------------------------------------
__global__ __launch_bounds__(256) void k_fin(
        const float* __restrict__ part_e, const float* __restrict__ part_v,
        const float* __restrict__ part_p, float* __restrict__ out) {
    int tid = threadIdx.x;
    float e = 0.0f, v = 0.0f, p = 0.0f;
    for (int i = tid; i < B; i += 256) {
        e += part_e[i];
        v += part_v[i];
        p += part_p[i];
    }
    #pragma unroll
    for (int d = 32; d; d >>= 1) {
        e += __shfl_xor(e, d);
        v += __shfl_xor(v, d);
        p += __shfl_xor(p, d);
    }
    __shared__ float sm[12];
    int lane = tid & 63, wv = tid >> 6;
    if (lane == 0) { sm[wv] = e; sm[4 + wv] = v; sm[8 + wv] = p; }
    __syncthreads();
    if (tid == 0) {
        float te = sm[0] + sm[1] + sm[2] + sm[3];
        float tv = sm[4] + sm[5] + sm[6] + sm[7];
        float tp = sm[8] + sm[9] + sm[10] + sm[11];
        out[0] = -tp / (float)(B * (T - 1));   // ppo_loss
        out[1] =  tv / (float)(B * T);         // value_loss
        out[2] = -te / (float)(B * T);         // entropy_loss
    }
}

// ---------------------------------------------------------------------------
extern "C" void kernel_launch(void* const* d_in, const int* in_sizes, int n_in,
                              void* d_out, int out_size, void* d_ws, size_t ws_size,
                              hipStream_t stream) {
    const float* rewards    = (const float*)d_in[0];
    const float* values     = (const float*)d_in[1];
    const float* logits     = (const float*)d_in[2];
    const float* logits_old = (const float*)d_in[3];
    const int*   dones      = (const int*)d_in[4];
    const int*   actions    = (const int*)d_in[5];

    float* part_e = (float*)d_ws;       // B floats
    float* part_v = part_e + B;         // B floats
    float* part_p = part_v + B;         // B floats

    k_fused<<<B, 512, 0, stream>>>(
        rewards, values, dones, actions, logits, logits_old,
        part_e, part_v, part_p);

    k_fin<<<1, 256, 0, stream>>>(part_e, part_v, part_p, (float*)d_out);
}